// Round 6
// baseline (17947.548 us; speedup 1.0000x reference)
//
#include <hip/hip_runtime.h>
#include <hip/hip_bf16.h>
#include <math.h>

// B=512, T=256, H=512, 4H=2048 gate cols, HALF=256, TGT=28
#define BB   512
#define TT   256
#define HH   512
#define NCOL 2048
#define HALF 256
#define TGT  28

typedef short short8 __attribute__((ext_vector_type(8)));
typedef float f32x4  __attribute__((ext_vector_type(4)));

__device__ __forceinline__ float bf2f(unsigned short u) {
    union { unsigned int i; float f; } v; v.i = ((unsigned int)u) << 16; return v.f;
}
__device__ __forceinline__ unsigned short f2bf(float x) {
    union { float f; unsigned int i; } v; v.f = x;
    unsigned int u = v.i;
    return (unsigned short)((u + 0x7FFFu + ((u >> 16) & 1u)) >> 16);
}
__device__ __forceinline__ float sigmoidf_(float x) {
    return 1.0f / (1.0f + __expf(-x));
}
__device__ __forceinline__ float tanhf_(float x) {
    x = fminf(fmaxf(x, -15.0f), 15.0f);
    float e = __expf(-2.0f * x);
    return (1.0f - e) / (1.0f + e);
}

// Fragment-order address for element (row r, k) of a 16-wide tile:
// plane layout [tile16][kchunk32][ (quad*16 + r15)*8 + k7 ]; tile stride 8192.
__device__ __forceinline__ int frag_addr(int r, int k) {
    return (r >> 4) * 8192 + (k >> 5) * 512 + ((((k >> 3) & 3) << 4) + (r & 15)) * 8 + (k & 7);
}

// prep: W_hh -> hi/lo bf16 planes in B-fragment order (col n = j*4+g);
// zero h buffer 0 and barrier counters; transpose seq -> seqT[t][b].
__global__ __launch_bounds__(256) void prep_kernel(
    const float* __restrict__ Whh, const float* __restrict__ seq,
    unsigned short* __restrict__ Whi, unsigned short* __restrict__ Wlo,
    unsigned short* __restrict__ h0hi, unsigned short* __restrict__ h0lo,
    float* __restrict__ seqT, int* __restrict__ cnt)
{
    int tid = blockIdx.x * 256 + threadIdx.x;   // grid 1024 -> 262144 threads
    h0hi[tid] = 0; h0lo[tid] = 0;
    if (tid < 4096) cnt[tid] = 0;
    if (tid < BB * TT) {
        int b = tid >> 8, t = tid & (TT - 1);
        seqT[t * BB + b] = seq[tid];
    }
    for (int e = tid; e < NCOL * HH; e += 262144) {
        int n = e >> 9;
        int k = e & (HH - 1);
        int j = n >> 2, g = n & 3;
        float w = Whh[(g * HH + j) * HH + k];
        unsigned short hi = f2bf(w);
        float lo = w - bf2f(hi);
        int a = frag_addr(n, k);
        Whi[a] = hi;
        Wlo[a] = f2bf(lo);
    }
}

// Persistent LSTM: all 256 steps in one kernel (regular launch; co-residency
// guaranteed: launch_bounds(256,2) caps VGPR<=256 and LDS=16.3KB -> >=2
// blocks/CU -> all 512 blocks resident).
// Grid 512 blocks x 256 thr. Block: 32 batch rows x 64 gate cols.
// Waves: (wn in {0,1}) x (wk k-half in {0,1}); wave = 32b x 32c x 256k.
// W fragments live in VGPRs for the whole kernel (128 VGPR/wave).
// K-split partial sums combine in LDS; ONLY the wk=0 wave carries the
// bias + x*W_ih init (wk=1 starts at 0) -- double-count was the round-4/5 bug.
// Per-step cross-block sync: per-row-group (32 blocks) counter barrier,
// __threadfence() (agent-scope, handles cross-XCD L2) + atomicAdd.
__global__ __launch_bounds__(256, 2) void lstm_persist(
    const unsigned short* __restrict__ Whi, const unsigned short* __restrict__ Wlo,
    unsigned short* __restrict__ h0hi, unsigned short* __restrict__ h0lo,
    unsigned short* __restrict__ h1hi, unsigned short* __restrict__ h1lo,
    const float* __restrict__ seqT,
    const float* __restrict__ wih,
    const float* __restrict__ bih, const float* __restrict__ bhh,
    int* __restrict__ cnt)
{
    const int bid  = blockIdx.x;
    const int bx   = (bid >> 3) & 31;            // col-block: cols bx*64..+64
    const int by   = (bid & 7) * 2 + (bid >> 8); // row-group: rows by*32..+32 (XCD-affine)
    const int tid  = threadIdx.x;
    const int lane = tid & 63;
    const int wave = tid >> 6;
    const int wn   = wave & 1, wk = wave >> 1;
    const int col16 = lane & 15, quad = lane >> 4;

    // ---- load W fragments into registers (once) ----
    short8 Wh[2][8], Wl[2][8];
    #pragma unroll
    for (int nt = 0; nt < 2; ++nt) {
        const int tb = (bx * 4 + wn * 2 + nt) * 8192 + lane * 8;
        #pragma unroll
        for (int kc = 0; kc < 8; ++kc) {
            const int a = tb + (wk * 8 + kc) * 512;
            Wh[nt][kc] = *(const short8*)(Whi + a);
            Wl[nt][kc] = *(const short8*)(Wlo + a);
        }
    }

    // bias + input weight per accumulator column (loaded once)
    float bn[2], wxn[2];
    #pragma unroll
    for (int nt = 0; nt < 2; ++nt) {
        int n   = bx * 64 + wn * 32 + nt * 16 + col16;
        int src = (n & 3) * HH + (n >> 2);
        bn[nt]  = bih[src] + bhh[src];
        wxn[nt] = wih[src];
    }

    float creg[2] = {0.0f, 0.0f};               // cell state, resident in regs

    __shared__ float gbuf[2][32][64];           // [k-half][b][col] partial gates
    __shared__ float xS[32];

    int* mycnt = cnt + by * TT;

    // epilogue h-store addresses (constant across t)
    int ha[2], cb[2];
    #pragma unroll
    for (int pp = 0; pp < 2; ++pp) {
        int idx = tid + pp * 256;
        int jj = idx & 15, bb = idx >> 4;
        ha[pp] = frag_addr(by * 32 + bb, bx * 16 + jj);
        cb[pp] = idx;
    }

    for (int t = 0; t < TT; ++t) {
        const unsigned short* hphi = (t & 1) ? h1hi : h0hi;
        const unsigned short* hplo = (t & 1) ? h1lo : h0lo;
        unsigned short* hnhi = (t & 1) ? h0hi : h1hi;
        unsigned short* hnlo = (t & 1) ? h0lo : h1lo;

        if (tid < 32) xS[tid] = seqT[t * BB + by * 32 + tid];

        if (t > 0 && tid == 0) {
            long spins = 0;
            while (__hip_atomic_load(&mycnt[t - 1], __ATOMIC_RELAXED,
                                     __HIP_MEMORY_SCOPE_AGENT) < 32) {
                __builtin_amdgcn_s_sleep(2);
                if (++spins > 200000000L) break;   // fail loud, never hang
            }
        }
        __syncthreads();
        __threadfence();   // acquire side: agent-scope, invalidates stale L1/L2

        // acc init: wk=0 wave carries bias + x*W_ih; wk=1 partial starts at 0
        f32x4 acc[2][2];
        #pragma unroll
        for (int mt = 0; mt < 2; ++mt) {
            #pragma unroll
            for (int nt = 0; nt < 2; ++nt) {
                #pragma unroll
                for (int r = 0; r < 4; ++r)
                    acc[mt][nt][r] = (wk == 0)
                        ? bn[nt] + xS[mt * 16 + quad * 4 + r] * wxn[nt]
                        : 0.0f;
            }
        }

        // K-loop over this wave's k-half; A from global (L2), B from registers.
        const int ab = by * 2 * 8192 + wk * 8 * 512 + lane * 8;
        #pragma unroll
        for (int kc = 0; kc < 8; ++kc) {
            short8 ah0 = *(const short8*)(hphi + ab + kc * 512);
            short8 al0 = *(const short8*)(hplo + ab + kc * 512);
            short8 ah1 = *(const short8*)(hphi + ab + 8192 + kc * 512);
            short8 al1 = *(const short8*)(hplo + ab + 8192 + kc * 512);
            acc[0][0] = __builtin_amdgcn_mfma_f32_16x16x32_bf16(ah0, Wh[0][kc], acc[0][0], 0, 0, 0);
            acc[0][1] = __builtin_amdgcn_mfma_f32_16x16x32_bf16(ah0, Wh[1][kc], acc[0][1], 0, 0, 0);
            acc[1][0] = __builtin_amdgcn_mfma_f32_16x16x32_bf16(ah1, Wh[0][kc], acc[1][0], 0, 0, 0);
            acc[1][1] = __builtin_amdgcn_mfma_f32_16x16x32_bf16(ah1, Wh[1][kc], acc[1][1], 0, 0, 0);
            acc[0][0] = __builtin_amdgcn_mfma_f32_16x16x32_bf16(ah0, Wl[0][kc], acc[0][0], 0, 0, 0);
            acc[0][1] = __builtin_amdgcn_mfma_f32_16x16x32_bf16(ah0, Wl[1][kc], acc[0][1], 0, 0, 0);
            acc[1][0] = __builtin_amdgcn_mfma_f32_16x16x32_bf16(ah1, Wl[0][kc], acc[1][0], 0, 0, 0);
            acc[1][1] = __builtin_amdgcn_mfma_f32_16x16x32_bf16(ah1, Wl[1][kc], acc[1][1], 0, 0, 0);
            acc[0][0] = __builtin_amdgcn_mfma_f32_16x16x32_bf16(al0, Wh[0][kc], acc[0][0], 0, 0, 0);
            acc[0][1] = __builtin_amdgcn_mfma_f32_16x16x32_bf16(al0, Wh[1][kc], acc[0][1], 0, 0, 0);
            acc[1][0] = __builtin_amdgcn_mfma_f32_16x16x32_bf16(al1, Wh[0][kc], acc[1][0], 0, 0, 0);
            acc[1][1] = __builtin_amdgcn_mfma_f32_16x16x32_bf16(al1, Wh[1][kc], acc[1][1], 0, 0, 0);
        }

        // k-partial gates -> LDS
        #pragma unroll
        for (int mt = 0; mt < 2; ++mt)
            #pragma unroll
            for (int nt = 0; nt < 2; ++nt)
                #pragma unroll
                for (int r = 0; r < 4; ++r)
                    gbuf[wk][mt * 16 + quad * 4 + r][wn * 32 + nt * 16 + col16] = acc[mt][nt][r];
        __syncthreads();

        // gate nonlinearities + c/h update (c in regs), h re-split to bf16 hi/lo
        #pragma unroll
        for (int pp = 0; pp < 2; ++pp) {
            int idx = cb[pp];
            int jj = idx & 15, bb = idx >> 4;
            f32x4 g0 = *(const f32x4*)(&gbuf[0][bb][jj * 4]);
            f32x4 g1 = *(const f32x4*)(&gbuf[1][bb][jj * 4]);
            float i_ = sigmoidf_(g0[0] + g1[0]);
            float f_ = sigmoidf_(g0[1] + g1[1]);
            float g_ = tanhf_(g0[2] + g1[2]);
            float o_ = sigmoidf_(g0[3] + g1[3]);
            float cn = f_ * creg[pp] + i_ * g_;
            creg[pp] = cn;
            float h  = o_ * tanhf_(cn);
            unsigned short hh = f2bf(h);
            float lo = h - bf2f(hh);
            hnhi[ha[pp]] = hh;
            hnlo[ha[pp]] = f2bf(lo);
        }

        __threadfence();   // release side: flush h stores to agent coherence point
        __syncthreads();
        if (tid == 0)
            atomicAdd(&mycnt[t], 1);   // device-scope by default [m20]
    }
}

// FC tail: hid = relu(h @ fc1_w.T + b); out = hid @ fc2_w.T + b. One block per b.
__global__ __launch_bounds__(256) void fc_kernel(
    const unsigned short* __restrict__ hhi, const unsigned short* __restrict__ hlo,
    const float* __restrict__ fc1w, const float* __restrict__ fc1b,
    const float* __restrict__ fc2w, const float* __restrict__ fc2b,
    float* __restrict__ out)
{
    __shared__ float hS[HH];
    __shared__ float hidS[HALF];
    const int b = blockIdx.x, tid = threadIdx.x;

    for (int k = tid; k < HH; k += 256) {
        int a = frag_addr(b, k);
        hS[k] = bf2f(hhi[a]) + bf2f(hlo[a]);
    }
    __syncthreads();

    float acc = fc1b[tid];
    const float4* wrow = (const float4*)(fc1w + tid * HH);
    #pragma unroll 4
    for (int k4 = 0; k4 < HH / 4; ++k4) {
        float4 w = wrow[k4];
        acc += w.x * hS[k4 * 4] + w.y * hS[k4 * 4 + 1]
             + w.z * hS[k4 * 4 + 2] + w.w * hS[k4 * 4 + 3];
    }
    hidS[tid] = fmaxf(acc, 0.0f);
    __syncthreads();

    if (tid < TGT) {
        float a2 = fc2b[tid];
        const float4* w2 = (const float4*)(fc2w + tid * HALF);
        #pragma unroll 4
        for (int k4 = 0; k4 < HALF / 4; ++k4) {
            float4 w = w2[k4];
            a2 += w.x * hidS[k4 * 4] + w.y * hidS[k4 * 4 + 1]
                + w.z * hidS[k4 * 4 + 2] + w.w * hidS[k4 * 4 + 3];
        }
        out[b * TGT + tid] = a2;
    }
}

extern "C" void kernel_launch(void* const* d_in, const int* in_sizes, int n_in,
                              void* d_out, int out_size, void* d_ws, size_t ws_size,
                              hipStream_t stream)
{
    const float* seq   = (const float*)d_in[0];
    const float* W_ih  = (const float*)d_in[1];
    const float* W_hh  = (const float*)d_in[2];
    const float* b_ih  = (const float*)d_in[3];
    const float* b_hh  = (const float*)d_in[4];
    const float* fc1_w = (const float*)d_in[5];
    const float* fc1_b = (const float*)d_in[6];
    const float* fc2_w = (const float*)d_in[7];
    const float* fc2_b = (const float*)d_in[8];
    float* out = (float*)d_out;

    // ws layout (6.52 MB total)
    unsigned short* us = (unsigned short*)d_ws;
    unsigned short* Whi  = us;                  // 1,048,576 shorts
    unsigned short* Wlo  = us + 1048576;
    unsigned short* h0hi = us + 2097152;        // 262,144 each
    unsigned short* h0lo = us + 2359296;
    unsigned short* h1hi = us + 2621440;
    unsigned short* h1lo = us + 2883584;        // shorts end at 3,145,728
    float* seqT = (float*)(us + 3145728);       // 131,072 floats
    int*   cnt  = (int*)(seqT + BB * TT);       // 4,096 ints

    prep_kernel<<<dim3(1024), dim3(256), 0, stream>>>(
        W_hh, seq, Whi, Wlo, h0hi, h0lo, seqT, cnt);

    lstm_persist<<<dim3(512), dim3(256), 0, stream>>>(
        Whi, Wlo, h0hi, h0lo, h1hi, h1lo,
        seqT, W_ih, b_ih, b_hh, cnt);

    // final h (t=255 writes buffer 0)
    fc_kernel<<<dim3(512), dim3(256), 0, stream>>>(
        h0hi, h0lo, fc1_w, fc1_b, fc2_w, fc2_b, out);
}

// Round 7
// 3304.725 us; speedup vs baseline: 5.4309x; 5.4309x over previous
//
#include <hip/hip_runtime.h>
#include <hip/hip_bf16.h>
#include <math.h>

// B=512, T=256, H=512, 4H=2048 gate cols, HALF=256, TGT=28
#define BB   512
#define TT   256
#define HH   512
#define NCOL 2048
#define HALF 256
#define TGT  28

typedef short short8 __attribute__((ext_vector_type(8)));
typedef float f32x4  __attribute__((ext_vector_type(4)));

__device__ __forceinline__ float bf2f(unsigned short u) {
    union { unsigned int i; float f; } v; v.i = ((unsigned int)u) << 16; return v.f;
}
__device__ __forceinline__ unsigned short f2bf(float x) {
    union { float f; unsigned int i; } v; v.f = x;
    unsigned int u = v.i;
    return (unsigned short)((u + 0x7FFFu + ((u >> 16) & 1u)) >> 16);
}
__device__ __forceinline__ float sigmoidf_(float x) {
    return 1.0f / (1.0f + __expf(-x));
}
__device__ __forceinline__ float tanhf_(float x) {
    x = fminf(fmaxf(x, -15.0f), 15.0f);
    float e = __expf(-2.0f * x);
    return (1.0f - e) / (1.0f + e);
}

// Fragment-order address for element (row r, k) of a 16-wide tile:
// plane layout [tile16][kchunk32][ (quad*16 + r15)*8 + k7 ]; tile stride 8192.
__device__ __forceinline__ int frag_addr(int r, int k) {
    return (r >> 4) * 8192 + (k >> 5) * 512 + ((((k >> 3) & 3) << 4) + (r & 15)) * 8 + (k & 7);
}

// prep: W_hh -> hi/lo bf16 planes in B-fragment order (col n = j*4+g);
// zero packed-h buffer 0 and barrier counters; transpose seq -> seqT[t][b].
__global__ __launch_bounds__(256) void prep_kernel(
    const float* __restrict__ Whh, const float* __restrict__ seq,
    unsigned short* __restrict__ Whi, unsigned short* __restrict__ Wlo,
    unsigned int* __restrict__ hpk0,
    float* __restrict__ seqT, int* __restrict__ cnt)
{
    int tid = blockIdx.x * 256 + threadIdx.x;   // grid 1024 -> 262144 threads
    hpk0[tid] = 0;                              // packed bf16 hi|lo zero
    if (tid < 4096) cnt[tid] = 0;
    if (tid < BB * TT) {
        int b = tid >> 8, t = tid & (TT - 1);
        seqT[t * BB + b] = seq[tid];
    }
    for (int e = tid; e < NCOL * HH; e += 262144) {
        int n = e >> 9;
        int k = e & (HH - 1);
        int j = n >> 2, g = n & 3;
        float w = Whh[(g * HH + j) * HH + k];
        unsigned short hi = f2bf(w);
        float lo = w - bf2f(hi);
        int a = frag_addr(n, k);
        Whi[a] = hi;
        Wlo[a] = f2bf(lo);
    }
}

// Unpack 8 packed h elements (hi|lo<<16) into hi/lo bf16 short8 fragments,
// loading through agent-scope relaxed atomics (sc0 sc1: bypass L1/L2, read
// the Infinity-Cache coherence point -- always fresh, NO fence needed).
__device__ __forceinline__ void load_frag_agent(
    const unsigned int* p, short8& hi, short8& lo)
{
    const unsigned long long* q = (const unsigned long long*)p;
    #pragma unroll
    for (int e = 0; e < 4; ++e) {
        unsigned long long u = __hip_atomic_load(q + e, __ATOMIC_RELAXED,
                                                 __HIP_MEMORY_SCOPE_AGENT);
        unsigned int w0 = (unsigned int)u;
        unsigned int w1 = (unsigned int)(u >> 32);
        hi[2 * e]     = (short)(w0 & 0xffffu);
        lo[2 * e]     = (short)(w0 >> 16);
        hi[2 * e + 1] = (short)(w1 & 0xffffu);
        lo[2 * e + 1] = (short)(w1 >> 16);
    }
}

// Persistent LSTM: all 256 steps in one kernel (regular launch; co-residency
// by construction: launch_bounds(256,2), LDS 16.5KB -> 2 blocks/CU -> all 512
// blocks resident). Block: 32 batch rows x 64 gate cols; waves (wn x wk).
// W fragments live in VGPRs for the whole kernel.
// h exchange: packed uint32 (bf16 hi | lo<<16) via agent-scope relaxed
// atomic stores/loads (write-through / coherence-point reads). NO
// __threadfence -- round-6's per-step buffer_wbl2 storm (71 us/step, 97%
// idle) is replaced by per-access coherence.
// Sync: per-row-group (32 blocks) counter; __syncthreads drains vmcnt
// (stores ack'd at coherence point) before the relaxed atomicAdd bump.
__global__ __launch_bounds__(256, 2) void lstm_persist(
    const unsigned short* __restrict__ Whi, const unsigned short* __restrict__ Wlo,
    unsigned int* __restrict__ hpk0, unsigned int* __restrict__ hpk1,
    const float* __restrict__ seqT,
    const float* __restrict__ wih,
    const float* __restrict__ bih, const float* __restrict__ bhh,
    int* __restrict__ cnt)
{
    const int bid  = blockIdx.x;
    const int bx   = (bid >> 3) & 31;            // col-block: cols bx*64..+64
    const int by   = (bid & 7) * 2 + (bid >> 8); // row-group: rows by*32..+32 (XCD-affine)
    const int tid  = threadIdx.x;
    const int lane = tid & 63;
    const int wave = tid >> 6;
    const int wn   = wave & 1, wk = wave >> 1;
    const int col16 = lane & 15, quad = lane >> 4;

    // ---- load W fragments into registers (once; normal cached loads,
    //      W is read-only so no coherence concern) ----
    short8 Wh[2][8], Wl[2][8];
    #pragma unroll
    for (int nt = 0; nt < 2; ++nt) {
        const int tb = (bx * 4 + wn * 2 + nt) * 8192 + lane * 8;
        #pragma unroll
        for (int kc = 0; kc < 8; ++kc) {
            const int a = tb + (wk * 8 + kc) * 512;
            Wh[nt][kc] = *(const short8*)(Whi + a);
            Wl[nt][kc] = *(const short8*)(Wlo + a);
        }
    }

    // bias + input weight per accumulator column (loaded once)
    float bn[2], wxn[2];
    #pragma unroll
    for (int nt = 0; nt < 2; ++nt) {
        int n   = bx * 64 + wn * 32 + nt * 16 + col16;
        int src = (n & 3) * HH + (n >> 2);
        bn[nt]  = bih[src] + bhh[src];
        wxn[nt] = wih[src];
    }

    float creg[2] = {0.0f, 0.0f};               // cell state, resident in regs

    __shared__ float gbuf[2][32][64];           // [k-half][b][col] partial gates
    __shared__ float xS[32];

    int* mycnt = cnt + by * TT;

    // epilogue h-store addresses (constant across t)
    int ha[2], cb[2];
    #pragma unroll
    for (int pp = 0; pp < 2; ++pp) {
        int idx = tid + pp * 256;
        int jj = idx & 15, bb = idx >> 4;
        ha[pp] = frag_addr(by * 32 + bb, bx * 16 + jj);
        cb[pp] = idx;
    }

    for (int t = 0; t < TT; ++t) {
        const unsigned int* hp = (t & 1) ? hpk1 : hpk0;
        unsigned int*       hn = (t & 1) ? hpk0 : hpk1;

        if (tid < 32) xS[tid] = seqT[t * BB + by * 32 + tid];

        if (t > 0 && tid == 0) {
            long spins = 0;
            while (__hip_atomic_load(&mycnt[t - 1], __ATOMIC_RELAXED,
                                     __HIP_MEMORY_SCOPE_AGENT) < 32) {
                __builtin_amdgcn_s_sleep(2);
                if (++spins > 200000000L) break;   // fail loud, never hang
            }
        }
        __syncthreads();

        // acc init: wk=0 wave carries bias + x*W_ih; wk=1 partial starts at 0
        f32x4 acc[2][2];
        #pragma unroll
        for (int mt = 0; mt < 2; ++mt) {
            #pragma unroll
            for (int nt = 0; nt < 2; ++nt) {
                #pragma unroll
                for (int r = 0; r < 4; ++r)
                    acc[mt][nt][r] = (wk == 0)
                        ? bn[nt] + xS[mt * 16 + quad * 4 + r] * wxn[nt]
                        : 0.0f;
            }
        }

        // K-loop over this wave's k-half; A via agent-scope loads (fresh from
        // IF$), B from registers.
        const int ab = by * 2 * 8192 + wk * 8 * 512 + lane * 8;
        #pragma unroll
        for (int kc = 0; kc < 8; ++kc) {
            short8 ah0, al0, ah1, al1;
            load_frag_agent(hp + ab + kc * 512,        ah0, al0);
            load_frag_agent(hp + ab + 8192 + kc * 512, ah1, al1);
            acc[0][0] = __builtin_amdgcn_mfma_f32_16x16x32_bf16(ah0, Wh[0][kc], acc[0][0], 0, 0, 0);
            acc[0][1] = __builtin_amdgcn_mfma_f32_16x16x32_bf16(ah0, Wh[1][kc], acc[0][1], 0, 0, 0);
            acc[1][0] = __builtin_amdgcn_mfma_f32_16x16x32_bf16(ah1, Wh[0][kc], acc[1][0], 0, 0, 0);
            acc[1][1] = __builtin_amdgcn_mfma_f32_16x16x32_bf16(ah1, Wh[1][kc], acc[1][1], 0, 0, 0);
            acc[0][0] = __builtin_amdgcn_mfma_f32_16x16x32_bf16(ah0, Wl[0][kc], acc[0][0], 0, 0, 0);
            acc[0][1] = __builtin_amdgcn_mfma_f32_16x16x32_bf16(ah0, Wl[1][kc], acc[0][1], 0, 0, 0);
            acc[1][0] = __builtin_amdgcn_mfma_f32_16x16x32_bf16(al1, Wh[0][kc], acc[1][0], 0, 0, 0);
            acc[1][1] = __builtin_amdgcn_mfma_f32_16x16x32_bf16(al1, Wh[1][kc], acc[1][1], 0, 0, 0);
            acc[0][0] = __builtin_amdgcn_mfma_f32_16x16x32_bf16(al0, Wh[0][kc], acc[0][0], 0, 0, 0);
            acc[0][1] = __builtin_amdgcn_mfma_f32_16x16x32_bf16(al0, Wh[1][kc], acc[0][1], 0, 0, 0);
            acc[1][0] = __builtin_amdgcn_mfma_f32_16x16x32_bf16(ah1, Wl[0][kc], acc[1][0], 0, 0, 0);
            acc[1][1] = __builtin_amdgcn_mfma_f32_16x16x32_bf16(ah1, Wl[1][kc], acc[1][1], 0, 0, 0);
        }

        // k-partial gates -> LDS
        #pragma unroll
        for (int mt = 0; mt < 2; ++mt)
            #pragma unroll
            for (int nt = 0; nt < 2; ++nt)
                #pragma unroll
                for (int r = 0; r < 4; ++r)
                    gbuf[wk][mt * 16 + quad * 4 + r][wn * 32 + nt * 16 + col16] = acc[mt][nt][r];
        __syncthreads();

        // gate nonlinearities + c/h update (c in regs), h packed + write-through
        #pragma unroll
        for (int pp = 0; pp < 2; ++pp) {
            int idx = cb[pp];
            int jj = idx & 15, bb = idx >> 4;
            f32x4 g0 = *(const f32x4*)(&gbuf[0][bb][jj * 4]);
            f32x4 g1 = *(const f32x4*)(&gbuf[1][bb][jj * 4]);
            float i_ = sigmoidf_(g0[0] + g1[0]);
            float f_ = sigmoidf_(g0[1] + g1[1]);
            float g_ = tanhf_(g0[2] + g1[2]);
            float o_ = sigmoidf_(g0[3] + g1[3]);
            float cn = f_ * creg[pp] + i_ * g_;
            creg[pp] = cn;
            float h  = o_ * tanhf_(cn);
            unsigned short hh = f2bf(h);
            float lo = h - bf2f(hh);
            unsigned int pk = (unsigned int)hh | ((unsigned int)f2bf(lo) << 16);
            __hip_atomic_store(&hn[ha[pp]], pk, __ATOMIC_RELAXED,
                               __HIP_MEMORY_SCOPE_AGENT);
        }

        // __syncthreads drains vmcnt(0): write-through stores are ack'd at the
        // coherence point before any thread bumps the counter.
        __syncthreads();
        if (tid == 0)
            atomicAdd(&mycnt[t], 1);   // relaxed device-scope RMW
    }
}

// FC tail: hid = relu(h @ fc1_w.T + b); out = hid @ fc2_w.T + b. One block per b.
__global__ __launch_bounds__(256) void fc_kernel(
    const unsigned int* __restrict__ hpk,
    const float* __restrict__ fc1w, const float* __restrict__ fc1b,
    const float* __restrict__ fc2w, const float* __restrict__ fc2b,
    float* __restrict__ out)
{
    __shared__ float hS[HH];
    __shared__ float hidS[HALF];
    const int b = blockIdx.x, tid = threadIdx.x;

    for (int k = tid; k < HH; k += 256) {
        unsigned int pk = hpk[frag_addr(b, k)];
        hS[k] = bf2f((unsigned short)(pk & 0xffffu)) +
                bf2f((unsigned short)(pk >> 16));
    }
    __syncthreads();

    float acc = fc1b[tid];
    const float4* wrow = (const float4*)(fc1w + tid * HH);
    #pragma unroll 4
    for (int k4 = 0; k4 < HH / 4; ++k4) {
        float4 w = wrow[k4];
        acc += w.x * hS[k4 * 4] + w.y * hS[k4 * 4 + 1]
             + w.z * hS[k4 * 4 + 2] + w.w * hS[k4 * 4 + 3];
    }
    hidS[tid] = fmaxf(acc, 0.0f);
    __syncthreads();

    if (tid < TGT) {
        float a2 = fc2b[tid];
        const float4* w2 = (const float4*)(fc2w + tid * HALF);
        #pragma unroll 4
        for (int k4 = 0; k4 < HALF / 4; ++k4) {
            float4 w = w2[k4];
            a2 += w.x * hidS[k4 * 4] + w.y * hidS[k4 * 4 + 1]
                + w.z * hidS[k4 * 4 + 2] + w.w * hidS[k4 * 4 + 3];
        }
        out[b * TGT + tid] = a2;
    }
}

extern "C" void kernel_launch(void* const* d_in, const int* in_sizes, int n_in,
                              void* d_out, int out_size, void* d_ws, size_t ws_size,
                              hipStream_t stream)
{
    const float* seq   = (const float*)d_in[0];
    const float* W_ih  = (const float*)d_in[1];
    const float* W_hh  = (const float*)d_in[2];
    const float* b_ih  = (const float*)d_in[3];
    const float* b_hh  = (const float*)d_in[4];
    const float* fc1_w = (const float*)d_in[5];
    const float* fc1_b = (const float*)d_in[6];
    const float* fc2_w = (const float*)d_in[7];
    const float* fc2_b = (const float*)d_in[8];
    float* out = (float*)d_out;

    // ws layout (~7.3 MB total)
    unsigned short* us = (unsigned short*)d_ws;
    unsigned short* Whi  = us;                       // 1,048,576 shorts (2 MB)
    unsigned short* Wlo  = us + 1048576;             // 2 MB
    unsigned int*   hpk0 = (unsigned int*)(us + 2097152);  // 262,144 uints (1 MB)
    unsigned int*   hpk1 = hpk0 + 262144;                  // 1 MB
    float* seqT = (float*)(hpk1 + 262144);           // 131,072 floats (512 KB)
    int*   cnt  = (int*)(seqT + BB * TT);            // 4,096 ints (16 KB)

    prep_kernel<<<dim3(1024), dim3(256), 0, stream>>>(
        W_hh, seq, Whi, Wlo, hpk0, seqT, cnt);

    lstm_persist<<<dim3(512), dim3(256), 0, stream>>>(
        Whi, Wlo, hpk0, hpk1, seqT, W_ih, b_ih, b_hh, cnt);

    // final h (t=255 writes buffer 0)
    fc_kernel<<<dim3(512), dim3(256), 0, stream>>>(
        hpk0, fc1_w, fc1_b, fc2_w, fc2_b, out);
}

// Round 8
// 1858.770 us; speedup vs baseline: 9.6556x; 1.7779x over previous
//
#include <hip/hip_runtime.h>
#include <hip/hip_bf16.h>
#include <math.h>

// B=512, T=256, H=512, 4H=2048 gate cols, HALF=256, TGT=28
#define BB   512
#define TT   256
#define HH   512
#define NCOL 2048
#define HALF 256
#define TGT  28

typedef short short8 __attribute__((ext_vector_type(8)));
typedef float f32x4  __attribute__((ext_vector_type(4)));

__device__ __forceinline__ float bf2f(unsigned short u) {
    union { unsigned int i; float f; } v; v.i = ((unsigned int)u) << 16; return v.f;
}
__device__ __forceinline__ unsigned short f2bf(float x) {
    union { float f; unsigned int i; } v; v.f = x;
    unsigned int u = v.i;
    return (unsigned short)((u + 0x7FFFu + ((u >> 16) & 1u)) >> 16);
}
__device__ __forceinline__ float sigmoidf_(float x) {
    return 1.0f / (1.0f + __expf(-x));
}
__device__ __forceinline__ float tanhf_(float x) {
    x = fminf(fmaxf(x, -15.0f), 15.0f);
    float e = __expf(-2.0f * x);
    return (1.0f - e) / (1.0f + e);
}

// Fragment-order address for element (row r, k) of a 16-wide tile:
// plane layout [tile16][kchunk32][ (quad*16 + r15)*8 + k7 ]; tile stride 8192.
__device__ __forceinline__ int frag_addr(int r, int k) {
    return (r >> 4) * 8192 + (k >> 5) * 512 + ((((k >> 3) & 3) << 4) + (r & 15)) * 8 + (k & 7);
}

// prep: W_hh -> hi/lo bf16 planes in B-fragment order (col n = j*4+g);
// zero h plane-buffer 0 and barrier counters; transpose seq -> seqT[t][b].
__global__ __launch_bounds__(256) void prep_kernel(
    const float* __restrict__ Whh, const float* __restrict__ seq,
    unsigned short* __restrict__ Whi, unsigned short* __restrict__ Wlo,
    unsigned short* __restrict__ h0hi, unsigned short* __restrict__ h0lo,
    float* __restrict__ seqT, int* __restrict__ cnt)
{
    int tid = blockIdx.x * 256 + threadIdx.x;   // grid 1024 -> 262144 threads
    h0hi[tid] = 0; h0lo[tid] = 0;
    if (tid < 4096) cnt[tid] = 0;
    if (tid < BB * TT) {
        int b = tid >> 8, t = tid & (TT - 1);
        seqT[t * BB + b] = seq[tid];
    }
    for (int e = tid; e < NCOL * HH; e += 262144) {
        int n = e >> 9;
        int k = e & (HH - 1);
        int j = n >> 2, g = n & 3;
        float w = Whh[(g * HH + j) * HH + k];
        unsigned short hi = f2bf(w);
        float lo = w - bf2f(hi);
        int a = frag_addr(n, k);
        Whi[a] = hi;
        Wlo[a] = f2bf(lo);
    }
}

// Persistent LSTM, all 256 steps. Grid 256 blocks x 512 thr = 1 block/CU
// (LDS 64KB, launch_bounds(512,2) caps VGPR<=256 -> all blocks resident).
// Block: 32 batch rows x 128 gate cols. Waves: wn in [0,4) x wk in {0,1}.
// W fragments (hi+lo, 32 cols x k-half) live in VGPRs: 128 VGPR/wave.
// Per step: stage A (hi+lo planes of this rg's 32 rows, 64KB) into LDS via
// agent-scope 8B atomic loads (IF$ coherence point -- XCD-mapping-agnostic),
// K-loop reads A via ds_read_b128 (no unpack VALU -- round-7's bottleneck),
// partial gates exchanged through a gbuf OVERLAYING the A-buffer (dead after
// the K-loop; extra __syncthreads covers the WAR).
// Sync: per-row-group (16 blocks) counter; __syncthreads drains vmcnt before
// the atomicAdd bump; consumers poll with relaxed agent loads.
__global__ __launch_bounds__(512, 2) void lstm_persist(
    const unsigned short* __restrict__ Whi, const unsigned short* __restrict__ Wlo,
    unsigned short* __restrict__ h0hi, unsigned short* __restrict__ h0lo,
    unsigned short* __restrict__ h1hi, unsigned short* __restrict__ h1lo,
    const float* __restrict__ seqT,
    const float* __restrict__ wih,
    const float* __restrict__ bih, const float* __restrict__ bhh,
    int* __restrict__ cnt)
{
    const int bid  = blockIdx.x;
    const int rg   = bid & 15;                   // row-group: rows rg*32..+32
    const int cb   = bid >> 4;                   // col-block: cols cb*128..+128
    const int tid  = threadIdx.x;
    const int lane = tid & 63;
    const int wave = tid >> 6;                   // 0..7
    const int wn   = wave & 3, wk = wave >> 2;   // 4 col-groups x 2 k-halves
    const int col16 = lane & 15, quad = lane >> 4;

    // LDS: A-stage buffer (64KB) overlaid with the gate-partial buffer (32KB).
    __shared__ __align__(16) unsigned char smem[65536];
    short* aS = (short*)smem;                      // [plane2][mt2][8192]
    float (*gS)[32][128] = (float (*)[32][128])smem; // [kh2][row32][col128]

    // ---- load W fragments into registers (once; read-only, cached) ----
    short8 Wh[2][8], Wl[2][8];
    #pragma unroll
    for (int nt = 0; nt < 2; ++nt) {
        const int tb = (cb * 8 + wn * 2 + nt) * 8192 + lane * 8;
        #pragma unroll
        for (int kc = 0; kc < 8; ++kc) {
            const int a = tb + (wk * 8 + kc) * 512;
            Wh[nt][kc] = *(const short8*)(Whi + a);
            Wl[nt][kc] = *(const short8*)(Wlo + a);
        }
    }

    // bias + input weight per accumulator column (loaded once)
    float bn[2], wxn[2];
    #pragma unroll
    for (int nt = 0; nt < 2; ++nt) {
        int n   = cb * 128 + wn * 32 + nt * 16 + col16;
        int src = (n & 3) * HH + (n >> 2);
        bn[nt]  = bih[src] + bhh[src];
        wxn[nt] = wih[src];
    }

    float creg[2] = {0.0f, 0.0f};   // cell state for this thread's 2 j's

    int* mycnt = cnt + rg * TT;

    // epilogue indexing (constant across t): thread -> (row bb, j-pair lj)
    const int bb = tid >> 4;
    const int lj = (tid & 15) * 2;
    const int hbase = frag_addr(rg * 32 + bb, cb * 32 + lj);  // pair is contiguous

    for (int t = 0; t < TT; ++t) {
        const unsigned short* hphi = (t & 1) ? h1hi : h0hi;
        const unsigned short* hplo = (t & 1) ? h1lo : h0lo;
        unsigned short* hnhi = (t & 1) ? h0hi : h1hi;
        unsigned short* hnlo = (t & 1) ? h0lo : h1lo;

        if (t > 0 && tid == 0) {
            long spins = 0;
            while (__hip_atomic_load(&mycnt[t - 1], __ATOMIC_RELAXED,
                                     __HIP_MEMORY_SCOPE_AGENT) < 16) {
                __builtin_amdgcn_s_sleep(2);
                if (++spins > 100000000L) break;   // fail loud, never hang
            }
        }
        __syncthreads();   // (1) everyone sees barrier passed; prior epilogue done

        // ---- stage A: 64KB (hi+lo planes, 2 m-tiles) via agent 8B loads ----
        const unsigned short* hp_pl[2] = {hphi, hplo};
        #pragma unroll
        for (int i = 0; i < 16; ++i) {
            int plane = i & 1;
            int flat  = (i >> 1) * 2048 + tid * 4;     // shorts within plane
            int mt    = flat >> 13;
            int inner = flat & 8191;
            const unsigned long long* src = (const unsigned long long*)
                (hp_pl[plane] + (rg * 2 + mt) * 8192 + inner);
            unsigned long long u = __hip_atomic_load(src, __ATOMIC_RELAXED,
                                                     __HIP_MEMORY_SCOPE_AGENT);
            *(unsigned long long*)(aS + plane * 16384 + flat) = u;
        }
        __syncthreads();   // (2) A staged

        // acc init: wk=0 wave carries bias + x*W_ih; wk=1 partial starts at 0
        f32x4 acc[2][2];
        if (wk == 0) {
            float xr[2][4];
            #pragma unroll
            for (int mt = 0; mt < 2; ++mt)
                #pragma unroll
                for (int r = 0; r < 4; ++r)
                    xr[mt][r] = seqT[t * BB + rg * 32 + mt * 16 + quad * 4 + r];
            #pragma unroll
            for (int mt = 0; mt < 2; ++mt)
                #pragma unroll
                for (int nt = 0; nt < 2; ++nt)
                    #pragma unroll
                    for (int r = 0; r < 4; ++r)
                        acc[mt][nt][r] = bn[nt] + xr[mt][r] * wxn[nt];
        } else {
            #pragma unroll
            for (int mt = 0; mt < 2; ++mt)
                #pragma unroll
                for (int nt = 0; nt < 2; ++nt)
                    #pragma unroll
                    for (int r = 0; r < 4; ++r)
                        acc[mt][nt][r] = 0.0f;
        }

        // ---- K-loop: A from LDS (ds_read_b128, no unpack), W from regs ----
        const int abase = wk * 8 * 512 + lane * 8;
        #pragma unroll
        for (int kc = 0; kc < 8; ++kc) {
            const int o = abase + kc * 512;
            short8 ah0 = *(const short8*)(aS + o);                  // hi, mt0
            short8 ah1 = *(const short8*)(aS + 8192 + o);           // hi, mt1
            short8 al0 = *(const short8*)(aS + 16384 + o);          // lo, mt0
            short8 al1 = *(const short8*)(aS + 16384 + 8192 + o);   // lo, mt1
            acc[0][0] = __builtin_amdgcn_mfma_f32_16x16x32_bf16(ah0, Wh[0][kc], acc[0][0], 0, 0, 0);
            acc[0][1] = __builtin_amdgcn_mfma_f32_16x16x32_bf16(ah0, Wh[1][kc], acc[0][1], 0, 0, 0);
            acc[1][0] = __builtin_amdgcn_mfma_f32_16x16x32_bf16(ah1, Wh[0][kc], acc[1][0], 0, 0, 0);
            acc[1][1] = __builtin_amdgcn_mfma_f32_16x16x32_bf16(ah1, Wh[1][kc], acc[1][1], 0, 0, 0);
            acc[0][0] = __builtin_amdgcn_mfma_f32_16x16x32_bf16(ah0, Wl[0][kc], acc[0][0], 0, 0, 0);
            acc[0][1] = __builtin_amdgcn_mfma_f32_16x16x32_bf16(ah0, Wl[1][kc], acc[0][1], 0, 0, 0);
            acc[1][0] = __builtin_amdgcn_mfma_f32_16x16x32_bf16(ah1, Wl[0][kc], acc[1][0], 0, 0, 0);
            acc[1][1] = __builtin_amdgcn_mfma_f32_16x16x32_bf16(ah1, Wl[1][kc], acc[1][1], 0, 0, 0);
            acc[0][0] = __builtin_amdgcn_mfma_f32_16x16x32_bf16(al0, Wh[0][kc], acc[0][0], 0, 0, 0);
            acc[0][1] = __builtin_amdgcn_mfma_f32_16x16x32_bf16(al0, Wh[1][kc], acc[0][1], 0, 0, 0);
            acc[1][0] = __builtin_amdgcn_mfma_f32_16x16x32_bf16(al1, Wh[0][kc], acc[1][0], 0, 0, 0);
            acc[1][1] = __builtin_amdgcn_mfma_f32_16x16x32_bf16(al1, Wh[1][kc], acc[1][1], 0, 0, 0);
        }
        __syncthreads();   // (3) all A reads done -> safe to overlay gS

        // k-partial gates -> gS overlay
        #pragma unroll
        for (int mt = 0; mt < 2; ++mt)
            #pragma unroll
            for (int nt = 0; nt < 2; ++nt)
                #pragma unroll
                for (int r = 0; r < 4; ++r)
                    gS[wk][mt * 16 + quad * 4 + r][wn * 32 + nt * 16 + col16] = acc[mt][nt][r];
        __syncthreads();   // (4) partials visible

        // gate nonlinearities + c/h update for 2 adjacent j's; paired 4B stores
        {
            f32x4 a0 = *(const f32x4*)(&gS[0][bb][lj * 4]);
            f32x4 b0 = *(const f32x4*)(&gS[1][bb][lj * 4]);
            f32x4 a1 = *(const f32x4*)(&gS[0][bb][(lj + 1) * 4]);
            f32x4 b1 = *(const f32x4*)(&gS[1][bb][(lj + 1) * 4]);
            float h_[2];
            #pragma unroll
            for (int e = 0; e < 2; ++e) {
                f32x4 ga = e ? a1 : a0, gb = e ? b1 : b0;
                float i_ = sigmoidf_(ga[0] + gb[0]);
                float f_ = sigmoidf_(ga[1] + gb[1]);
                float g_ = tanhf_(ga[2] + gb[2]);
                float o_ = sigmoidf_(ga[3] + gb[3]);
                float cn = f_ * creg[e] + i_ * g_;
                creg[e] = cn;
                h_[e] = o_ * tanhf_(cn);
            }
            unsigned short hh0 = f2bf(h_[0]), hh1 = f2bf(h_[1]);
            unsigned int hipk = (unsigned int)hh0 | ((unsigned int)hh1 << 16);
            unsigned int lopk = (unsigned int)f2bf(h_[0] - bf2f(hh0))
                              | ((unsigned int)f2bf(h_[1] - bf2f(hh1)) << 16);
            __hip_atomic_store((unsigned int*)(hnhi + hbase), hipk,
                               __ATOMIC_RELAXED, __HIP_MEMORY_SCOPE_AGENT);
            __hip_atomic_store((unsigned int*)(hnlo + hbase), lopk,
                               __ATOMIC_RELAXED, __HIP_MEMORY_SCOPE_AGENT);
        }

        __syncthreads();   // (5) drains vmcnt: stores ack'd at coherence point
        if (tid == 0)
            atomicAdd(&mycnt[t], 1);
    }
}

// FC tail: hid = relu(h @ fc1_w.T + b); out = hid @ fc2_w.T + b. One block per b.
__global__ __launch_bounds__(256) void fc_kernel(
    const unsigned short* __restrict__ hhi, const unsigned short* __restrict__ hlo,
    const float* __restrict__ fc1w, const float* __restrict__ fc1b,
    const float* __restrict__ fc2w, const float* __restrict__ fc2b,
    float* __restrict__ out)
{
    __shared__ float hS[HH];
    __shared__ float hidS[HALF];
    const int b = blockIdx.x, tid = threadIdx.x;

    for (int k = tid; k < HH; k += 256) {
        int a = frag_addr(b, k);
        hS[k] = bf2f(hhi[a]) + bf2f(hlo[a]);
    }
    __syncthreads();

    float acc = fc1b[tid];
    const float4* wrow = (const float4*)(fc1w + tid * HH);
    #pragma unroll 4
    for (int k4 = 0; k4 < HH / 4; ++k4) {
        float4 w = wrow[k4];
        acc += w.x * hS[k4 * 4] + w.y * hS[k4 * 4 + 1]
             + w.z * hS[k4 * 4 + 2] + w.w * hS[k4 * 4 + 3];
    }
    hidS[tid] = fmaxf(acc, 0.0f);
    __syncthreads();

    if (tid < TGT) {
        float a2 = fc2b[tid];
        const float4* w2 = (const float4*)(fc2w + tid * HALF);
        #pragma unroll 4
        for (int k4 = 0; k4 < HALF / 4; ++k4) {
            float4 w = w2[k4];
            a2 += w.x * hidS[k4 * 4] + w.y * hidS[k4 * 4 + 1]
                + w.z * hidS[k4 * 4 + 2] + w.w * hidS[k4 * 4 + 3];
        }
        out[b * TGT + tid] = a2;
    }
}

extern "C" void kernel_launch(void* const* d_in, const int* in_sizes, int n_in,
                              void* d_out, int out_size, void* d_ws, size_t ws_size,
                              hipStream_t stream)
{
    const float* seq   = (const float*)d_in[0];
    const float* W_ih  = (const float*)d_in[1];
    const float* W_hh  = (const float*)d_in[2];
    const float* b_ih  = (const float*)d_in[3];
    const float* b_hh  = (const float*)d_in[4];
    const float* fc1_w = (const float*)d_in[5];
    const float* fc1_b = (const float*)d_in[6];
    const float* fc2_w = (const float*)d_in[7];
    const float* fc2_b = (const float*)d_in[8];
    float* out = (float*)d_out;

    // ws layout (~6.6 MB total)
    unsigned short* us = (unsigned short*)d_ws;
    unsigned short* Whi  = us;                  // 1,048,576 shorts (2 MB)
    unsigned short* Wlo  = us + 1048576;        // 2 MB
    unsigned short* h0hi = us + 2097152;        // 262,144 shorts each
    unsigned short* h0lo = us + 2359296;
    unsigned short* h1hi = us + 2621440;
    unsigned short* h1lo = us + 2883584;        // shorts end at 3,145,728
    float* seqT = (float*)(us + 3145728);       // 131,072 floats (512 KB)
    int*   cnt  = (int*)(seqT + BB * TT);       // 4,096 ints (16 KB)

    prep_kernel<<<dim3(1024), dim3(256), 0, stream>>>(
        W_hh, seq, Whi, Wlo, h0hi, h0lo, seqT, cnt);

    lstm_persist<<<dim3(256), dim3(512), 0, stream>>>(
        Whi, Wlo, h0hi, h0lo, h1hi, h1lo,
        seqT, W_ih, b_ih, b_hh, cnt);

    // final h (t=255 writes buffer 0)
    fc_kernel<<<dim3(512), dim3(256), 0, stream>>>(
        h0hi, h0lo, fc1_w, fc1_b, fc2_w, fc2_b, out);
}